// Round 6
// baseline (424.793 us; speedup 1.0000x reference)
//
#include <hip/hip_runtime.h>
#include <stdint.h>

// Problem constants: B=1, S=2048, D=4096, H=32, KV=8, HD=128, NREP=4
#define SCALE_F 0.08838834764831845f
#define LOG2E_F 1.4426950408889634f
#define QS_F (SCALE_F * LOG2E_F)

typedef __bf16 bf16x8_t __attribute__((ext_vector_type(8)));
typedef unsigned short u16x8 __attribute__((ext_vector_type(8)));
typedef float f32x4 __attribute__((ext_vector_type(4)));
typedef float f32x16 __attribute__((ext_vector_type(16)));

__device__ __forceinline__ unsigned short f2bf(float f) {
  unsigned int u = __float_as_uint(f);
  unsigned int r = ((u >> 16) & 1u) + 0x7FFFu;  // RNE
  return (unsigned short)((u + r) >> 16);
}
__device__ __forceinline__ float bf2f(unsigned short s) {
  return __uint_as_float(((unsigned int)s) << 16);
}
__device__ __forceinline__ f32x4 mfma16(u16x8 a, u16x8 b, f32x4 c) {
  return __builtin_amdgcn_mfma_f32_16x16x32_bf16(
      __builtin_bit_cast(bf16x8_t, a), __builtin_bit_cast(bf16x8_t, b), c, 0, 0, 0);
}
__device__ __forceinline__ f32x16 mfma32(u16x8 a, u16x8 b, f32x16 c) {
  return __builtin_amdgcn_mfma_f32_32x32x16_bf16(
      __builtin_bit_cast(bf16x8_t, a), __builtin_bit_cast(bf16x8_t, b), c, 0, 0, 0);
}
__device__ __forceinline__ unsigned int cvtpk(float lo, float hi) {
  unsigned int r;
  asm("v_cvt_pk_bf16_f32 %0, %1, %2" : "=v"(r) : "v"(lo), "v"(hi));
  return r;
}
__device__ __forceinline__ float exp2_hw(float x) {  // D = 2^S0
  float r;
  asm("v_exp_f32 %0, %1" : "=v"(r) : "v"(x));
  return r;
}
__device__ __forceinline__ void gload_lds16(const void* g, void* l) {
  __builtin_amdgcn_global_load_lds((const __attribute__((address_space(1))) void*)g,
                                   (__attribute__((address_space(3))) void*)l, 16, 0, 0);
}

// ---------------- f32 -> bf16 convert ----------------
__global__ void cvtk(const float* __restrict__ in, unsigned short* __restrict__ out, int n) {
  int i = (blockIdx.x * blockDim.x + threadIdx.x) * 4;
  if (i >= n) return;
  float4 v = *(const float4*)(in + i);
  unsigned int p0 = (unsigned int)f2bf(v.x) | ((unsigned int)f2bf(v.y) << 16);
  unsigned int p1 = (unsigned int)f2bf(v.z) | ((unsigned int)f2bf(v.w) << 16);
  *(uint2*)(out + i) = make_uint2(p0, p1);
}

// ---------------- K: retile into chunk-transposed tile images (rope already applied) ----
__global__ void ktile(const unsigned short* __restrict__ QKV, unsigned short* __restrict__ Ktil) {
  int b = blockIdx.x;  // kvg*64 + kvt
  int kvg = b >> 6, kvt = b & 63;
  int tid = threadIdx.x;
#pragma unroll
  for (int cc = 0; cc < 2; ++cc) {
    int c = tid + cc * 256;
    int s = c >> 5, r = c & 31;
    int key = kvt * 32 + r;
    *(uint4*)&Ktil[(size_t)b * 4096 + c * 8] =
        *(const uint4*)&QKV[(size_t)key * 6144 + 4096 + kvg * 128 + s * 8];
  }
}

// ---------------- V: transpose + retile ----------------
__global__ void vtile(const unsigned short* __restrict__ QKV, unsigned short* __restrict__ Vtil) {
  int b = blockIdx.x;  // kvg*64 + kvt
  int kvg = b >> 6, kvt = b & 63;
  int tid = threadIdx.x;
#pragma unroll
  for (int cc = 0; cc < 2; ++cc) {
    int c = tid + cc * 256;
    int v = c >> 7, hd = c & 127;
    unsigned short o[8];
#pragma unroll
    for (int t = 0; t < 8; ++t)
      o[t] = QKV[(size_t)(kvt * 32 + v * 8 + t) * 6144 + 5120 + kvg * 128 + hd];
    *(uint4*)&Vtil[(size_t)b * 4096 + c * 8] = *(uint4*)o;
  }
}

// ---------------- QKV GEMM: 256x192 tiles, 256 blocks, fused RoPE epilogue ----------------
// 2 fat phases per K-tile (mh halves, 24 MFMA each). All 7 stages for tile t+1 issued at
// tile-t start (slot e free: its readers lgkmcnt(0)-drained before the prior boundary
// barrier); one vmcnt(0) at max distance (~1 K-tile) before the boundary barrier.
__global__ __launch_bounds__(512, 2) void gemm_qkv(const unsigned short* __restrict__ A,
                                                   const unsigned short* __restrict__ BT,
                                                   const float* __restrict__ fc,
                                                   unsigned short* __restrict__ C) {
  const int K = 4096, N = 6144;
  __shared__ __align__(16) unsigned short smem[2 * 28672];  // 112 KiB
  const int tid = threadIdx.x;
  const int w = tid >> 6, l = tid & 63;
  const int wm = w >> 2, wn = w & 3;
  const int c16 = l & 15, h4 = l >> 4;
  const int wg = ((int)blockIdx.x & 7) * 32 + ((int)blockIdx.x >> 3);  // T1 XCD swizzle
  const int m0 = (wg & 7) << 8, n0 = (wg >> 3) * 192;

  int growA[4], gcolA[4], growB[3], gcolB[3];
#pragma unroll
  for (int p = 0; p < 4; ++p) {
    int c = p * 512 + tid, ll = c & 63;
    growA[p] = ((c >> 6) & 15) * 16 + (ll & 15);
    gcolA[p] = (c >> 10) * 32 + ((ll >> 4) << 3);
  }
#pragma unroll
  for (int p = 0; p < 3; ++p) {
    int c = p * 512 + tid, ll = c & 63, f6 = c >> 6;
    int kc = (f6 >= 12) ? 1 : 0;
    growB[p] = (f6 - 12 * kc) * 16 + (ll & 15);
    gcolB[p] = kc * 32 + ((ll >> 4) << 3);
  }
  auto stageA = [&](int e, int ks, int p) {
    gload_lds16(A + (size_t)(m0 + growA[p]) * K + ks + gcolA[p],
                &smem[e * 28672 + (p * 512 + tid) * 8]);
  };
  auto stageB = [&](int e, int ks, int p) {
    gload_lds16(BT + (size_t)(n0 + growB[p]) * K + ks + gcolB[p],
                &smem[e * 28672 + 16384 + (p * 512 + tid) * 8]);
  };

  f32x4 acc[2][4][3];
#pragma unroll
  for (int mh = 0; mh < 2; ++mh)
#pragma unroll
    for (int mf = 0; mf < 4; ++mf)
#pragma unroll
      for (int nf = 0; nf < 3; ++nf)
#pragma unroll
        for (int r = 0; r < 4; ++r) acc[mh][mf][nf][r] = 0.f;

  // prologue: tile 0 -> slot 0
  stageA(0, 0, 0); stageA(0, 0, 1); stageA(0, 0, 2); stageA(0, 0, 3);
  stageB(0, 0, 0); stageB(0, 0, 1); stageB(0, 0, 2);
  asm volatile("s_waitcnt vmcnt(0)" ::: "memory");
  __builtin_amdgcn_sched_barrier(0);
  asm volatile("s_barrier" ::: "memory");

  const int nt = K >> 6;
  for (int t = 0; t < nt; ++t) {
    const int d = t & 1, e = d ^ 1;
    const int dA = d * 28672, dB = dA + 16384;
    const int ks = ((t + 1 < nt) ? t + 1 : t) << 6;  // clamp: redundant, never read
    // stage ALL of tile t+1 into slot e
    stageA(e, ks, 0); stageA(e, ks, 1); stageA(e, ks, 2); stageA(e, ks, 3);
    stageB(e, ks, 0); stageB(e, ks, 1); stageB(e, ks, 2);
    // phase 0 (mh=0): 8 A-frags + 6 B-frags, 24 MFMA
    u16x8 af[2][4], bfr[2][3];
#pragma unroll
    for (int kc = 0; kc < 2; ++kc) {
#pragma unroll
      for (int mf = 0; mf < 4; ++mf)
        af[kc][mf] = *(const u16x8*)&smem[dA + ((kc * 16 + wm * 8 + mf) * 64 + l) * 8];
#pragma unroll
      for (int nf = 0; nf < 3; ++nf)
        bfr[kc][nf] = *(const u16x8*)&smem[dB + ((kc * 12 + wn * 3 + nf) * 64 + l) * 8];
    }
    asm volatile("s_barrier" ::: "memory");
    asm volatile("s_waitcnt lgkmcnt(0)" ::: "memory");
    __builtin_amdgcn_sched_barrier(0);
    __builtin_amdgcn_s_setprio(1);
#pragma unroll
    for (int kc = 0; kc < 2; ++kc)
#pragma unroll
      for (int mf = 0; mf < 4; ++mf)
#pragma unroll
        for (int nf = 0; nf < 3; ++nf)
          acc[0][mf][nf] = mfma16(af[kc][mf], bfr[kc][nf], acc[0][mf][nf]);
    __builtin_amdgcn_s_setprio(0);
    __builtin_amdgcn_sched_barrier(0);
    asm volatile("s_barrier" ::: "memory");
    // phase 1 (mh=1): 8 A-frags, reuse bfr, 24 MFMA
    u16x8 af2[2][4];
#pragma unroll
    for (int kc = 0; kc < 2; ++kc)
#pragma unroll
      for (int mf = 0; mf < 4; ++mf)
        af2[kc][mf] = *(const u16x8*)&smem[dA + ((kc * 16 + wm * 8 + 4 + mf) * 64 + l) * 8];
    asm volatile("s_waitcnt lgkmcnt(0)" ::: "memory");
    __builtin_amdgcn_sched_barrier(0);
    __builtin_amdgcn_s_setprio(1);
#pragma unroll
    for (int kc = 0; kc < 2; ++kc)
#pragma unroll
      for (int mf = 0; mf < 4; ++mf)
#pragma unroll
        for (int nf = 0; nf < 3; ++nf)
          acc[1][mf][nf] = mfma16(af2[kc][mf], bfr[kc][nf], acc[1][mf][nf]);
    __builtin_amdgcn_s_setprio(0);
    __builtin_amdgcn_sched_barrier(0);
    asm volatile("s_waitcnt vmcnt(0)" ::: "memory");  // tile t+1 landed (max distance)
    asm volatile("s_barrier" ::: "memory");            // boundary
  }

  // epilogue with fused RoPE: cols<4096 -> Q rope * (SCALE*log2e); 4096..5119 -> K rope;
  // >=5120 -> V passthrough. Pair partner lives in adjacent lane (c16^1): shfl_xor(1).
#pragma unroll
  for (int mh = 0; mh < 2; ++mh)
#pragma unroll
    for (int mf = 0; mf < 4; ++mf)
#pragma unroll
      for (int nf = 0; nf < 3; ++nf) {
        const int colbase = n0 + wn * 48 + nf * 16;  // type uniform over c16 (16 | bounds)
#pragma unroll
        for (int r = 0; r < 4; ++r) {
          int row = m0 + wm * 128 + mh * 64 + mf * 16 + h4 * 4 + r;
          float v = acc[mh][mf][nf][r];
          if (colbase < 5120) {
            float other = __shfl_xor(v, 1, 64);
            int j = ((colbase & 127) >> 1) + (c16 >> 1);
            float2 csn = *(const float2*)&fc[((size_t)row * 64 + j) * 2];
            float o = (c16 & 1) ? (other * csn.y + v * csn.x) : (v * csn.x - other * csn.y);
            v = (colbase < 4096) ? o * QS_F : o;
          }
          C[(size_t)row * N + colbase + c16] = f2bf(v);
        }
      }
}

// ---------------- Out-proj GEMM: 128x256 tiles, 256 blocks, f32 out ----------------
// Same restructured schedule: all 6 stages at tile start, 2 fat phases (kc halves,
// 16 MFMA each), one vmcnt(0) at max distance.
__global__ __launch_bounds__(512, 2) void gemm_o(const unsigned short* __restrict__ A,
                                                 const unsigned short* __restrict__ BT,
                                                 float* __restrict__ C) {
  const int K = 4096, N = 4096;
  __shared__ __align__(16) unsigned short smem[2 * 24576];  // 96 KiB
  const int tid = threadIdx.x;
  const int w = tid >> 6, l = tid & 63;
  const int wm = w >> 2, wn = w & 3;
  const int c16 = l & 15, h4 = l >> 4;
  const int wg = ((int)blockIdx.x & 7) * 32 + ((int)blockIdx.x >> 3);  // T1 XCD swizzle
  const int m0 = (wg & 15) << 7, n0 = (wg >> 4) << 8;

  int growA[2], gcolA[2], growB[4], gcolB[4];
#pragma unroll
  for (int p = 0; p < 2; ++p) {
    int c = p * 512 + tid, ll = c & 63;
    growA[p] = ((c >> 6) & 7) * 16 + (ll & 15);
    gcolA[p] = (c >> 9) * 32 + ((ll >> 4) << 3);
  }
#pragma unroll
  for (int p = 0; p < 4; ++p) {
    int c = p * 512 + tid, ll = c & 63;
    growB[p] = ((c >> 6) & 15) * 16 + (ll & 15);
    gcolB[p] = (c >> 10) * 32 + ((ll >> 4) << 3);
  }
  auto stageA = [&](int e, int ks, int p) {
    gload_lds16(A + (size_t)(m0 + growA[p]) * K + ks + gcolA[p],
                &smem[e * 24576 + (p * 512 + tid) * 8]);
  };
  auto stageB = [&](int e, int ks, int p) {
    gload_lds16(BT + (size_t)(n0 + growB[p]) * K + ks + gcolB[p],
                &smem[e * 24576 + 8192 + (p * 512 + tid) * 8]);
  };

  f32x4 acc[4][4];
#pragma unroll
  for (int mf = 0; mf < 4; ++mf)
#pragma unroll
    for (int nc = 0; nc < 4; ++nc)
#pragma unroll
      for (int r = 0; r < 4; ++r) acc[mf][nc][r] = 0.f;

  stageA(0, 0, 0); stageA(0, 0, 1);
  stageB(0, 0, 0); stageB(0, 0, 1); stageB(0, 0, 2); stageB(0, 0, 3);
  asm volatile("s_waitcnt vmcnt(0)" ::: "memory");
  __builtin_amdgcn_sched_barrier(0);
  asm volatile("s_barrier" ::: "memory");

  const int nt = K >> 6;
  for (int t = 0; t < nt; ++t) {
    const int d = t & 1, e = d ^ 1;
    const int dA = d * 24576, dB = dA + 8192;
    const int ks = ((t + 1 < nt) ? t + 1 : t) << 6;
    stageA(e, ks, 0); stageA(e, ks, 1);
    stageB(e, ks, 0); stageB(e, ks, 1); stageB(e, ks, 2); stageB(e, ks, 3);
#pragma unroll
    for (int kc = 0; kc < 2; ++kc) {
      u16x8 af[4], bfr[4];
#pragma unroll
      for (int mf = 0; mf < 4; ++mf)
        af[mf] = *(const u16x8*)&smem[dA + ((kc * 8 + wm * 4 + mf) * 64 + l) * 8];
#pragma unroll
      for (int nc = 0; nc < 4; ++nc)
        bfr[nc] = *(const u16x8*)&smem[dB + ((kc * 16 + wn * 4 + nc) * 64 + l) * 8];
      if (kc == 0) asm volatile("s_barrier" ::: "memory");
      asm volatile("s_waitcnt lgkmcnt(0)" ::: "memory");
      __builtin_amdgcn_sched_barrier(0);
      __builtin_amdgcn_s_setprio(1);
#pragma unroll
      for (int mf = 0; mf < 4; ++mf)
#pragma unroll
        for (int nc = 0; nc < 4; ++nc)
          acc[mf][nc] = mfma16(af[mf], bfr[nc], acc[mf][nc]);
      __builtin_amdgcn_s_setprio(0);
      __builtin_amdgcn_sched_barrier(0);
      if (kc == 0) asm volatile("s_barrier" ::: "memory");
    }
    asm volatile("s_waitcnt vmcnt(0)" ::: "memory");
    asm volatile("s_barrier" ::: "memory");  // boundary
  }

#pragma unroll
  for (int mf = 0; mf < 4; ++mf)
#pragma unroll
    for (int nc = 0; nc < 4; ++nc)
#pragma unroll
      for (int r = 0; r < 4; ++r) {
        int row = m0 + wm * 64 + mf * 16 + h4 * 4 + r;
        int col = n0 + wn * 64 + nc * 16 + c16;
        C[(size_t)row * N + col] = acc[mf][nc][r];
      }
}

// ---------------- flash attention (causal GQA), 32x32x16 swapped-MFMA ----------------
__global__ __launch_bounds__(256) void attnk(const unsigned short* __restrict__ Q,
                                             const unsigned short* __restrict__ Ktil,
                                             const unsigned short* __restrict__ Vtil,
                                             unsigned short* __restrict__ Ao) {
  __shared__ __align__(16) unsigned short Kbuf[2][4096];  // 8KB per buffer
  __shared__ __align__(16) unsigned short Vbuf[2][4096];
  const int tid = threadIdx.x;
  const int w = tid >> 6, l = tid & 63;
  const int q31 = l & 31, hi = l >> 5;
  const int b = blockIdx.x;
  const int kvg = b & 7;             // kv-group -> XCD affinity
  const int qg = 63 - (b >> 3);      // descending work length for backfill balance
  const int head = kvg * 4 + w;
  const int qrow = qg * 32 + q31;

  u16x8 qf[8];
#pragma unroll
  for (int kc = 0; kc < 8; ++kc)
    qf[kc] = *(const u16x8*)&Q[(size_t)qrow * 6144 + head * 128 + kc * 16 + hi * 8];

  f32x16 accO[4];
#pragma unroll
  for (int f = 0; f < 4; ++f)
#pragma unroll
    for (int r = 0; r < 16; ++r) accO[f][r] = 0.f;
  float m_run = -1e30f, l_run = 0.f;

  const unsigned short* ktb = Ktil + (size_t)kvg * 64 * 4096;
  const unsigned short* vtb = Vtil + (size_t)kvg * 64 * 4096;
  auto STAGE = [&](int d, int t) {
    const unsigned short* ks = ktb + (size_t)t * 4096 + w * 1024 + l * 8;
    const unsigned short* vs = vtb + (size_t)t * 4096 + w * 1024 + l * 8;
    gload_lds16(ks, &Kbuf[d][w * 1024 + l * 8]);
    gload_lds16(ks + 512, &Kbuf[d][w * 1024 + 512 + l * 8]);
    gload_lds16(vs, &Vbuf[d][w * 1024 + l * 8]);
    gload_lds16(vs + 512, &Vbuf[d][w * 1024 + 512 + l * 8]);
  };

  STAGE(0, 0);
  int cur = 0;
  for (int kvt = 0; kvt <= qg; ++kvt) {
    __builtin_amdgcn_s_barrier();
    __builtin_amdgcn_sched_barrier(0);
    if (kvt < qg) {
      STAGE(cur ^ 1, kvt + 1);
      asm volatile("s_waitcnt vmcnt(4)" ::: "memory");
    } else {
      asm volatile("s_waitcnt vmcnt(0)" ::: "memory");
    }
    __builtin_amdgcn_s_barrier();
    __builtin_amdgcn_sched_barrier(0);

    f32x16 s;
#pragma unroll
    for (int r = 0; r < 16; ++r) s[r] = 0.f;
#pragma unroll
    for (int kc = 0; kc < 8; ++kc) {
      u16x8 kf = *(const u16x8*)&Kbuf[cur][((2 * kc + hi) * 32 + q31) * 8];
      s = mfma32(kf, qf[kc], s);
    }

    if (kvt == qg) {
#pragma unroll
      for (int r = 0; r < 16; ++r) {
        int key = (r & 3) + 8 * (r >> 2) + 4 * hi;
        if (key > q31) s[r] = -1e30f;
      }
    }

    float pm = s[0];
#pragma unroll
    for (int r = 1; r < 16; ++r) pm = fmaxf(pm, s[r]);
    pm = fmaxf(pm, __shfl_xor(pm, 32, 64));
    if (!__all(pm - m_run <= 8.f)) {  // T13 defer-max (2^8 bound)
      float mn = fmaxf(m_run, pm);
      float al = exp2_hw(m_run - mn);
      m_run = mn;
      l_run *= al;
#pragma unroll
      for (int f = 0; f < 4; ++f)
#pragma unroll
        for (int r = 0; r < 16; ++r) accO[f][r] *= al;
    }
    float p[16], ls = 0.f;
#pragma unroll
    for (int r = 0; r < 16; ++r) { p[r] = exp2_hw(s[r] - m_run); ls += p[r]; }
    l_run += ls + __shfl_xor(ls, 32, 64);

    unsigned int wv[8], wp[8];
#pragma unroll
    for (int i = 0; i < 8; ++i) wv[i] = cvtpk(p[2 * i], p[2 * i + 1]);
#pragma unroll
    for (int i = 0; i < 8; ++i) wp[i] = (unsigned int)__shfl_xor((int)wv[i], 32, 64);
    union { unsigned int u[4]; u16x8 v; } pf0, pf1;
    pf0.u[0] = hi ? wp[2] : wv[0];
    pf0.u[1] = hi ? wp[3] : wv[1];
    pf0.u[2] = hi ? wv[2] : wp[0];
    pf0.u[3] = hi ? wv[3] : wp[1];
    pf1.u[0] = hi ? wp[6] : wv[4];
    pf1.u[1] = hi ? wp[7] : wv[5];
    pf1.u[2] = hi ? wv[6] : wp[4];
    pf1.u[3] = hi ? wv[7] : wp[5];

#pragma unroll
    for (int f = 0; f < 4; ++f) {
      u16x8 vf0 = *(const u16x8*)&Vbuf[cur][((hi) * 128 + f * 32 + q31) * 8];
      u16x8 vf1 = *(const u16x8*)&Vbuf[cur][((2 + hi) * 128 + f * 32 + q31) * 8];
      accO[f] = mfma32(vf0, pf0.v, accO[f]);
      accO[f] = mfma32(vf1, pf1.v, accO[f]);
    }
    cur ^= 1;
  }

  float linv = 1.0f / l_run;
  unsigned short* orow = Ao + (size_t)qrow * 4096 + head * 128;
#pragma unroll
  for (int f = 0; f < 4; ++f)
#pragma unroll
    for (int g4 = 0; g4 < 4; ++g4) {
      unsigned int lo = (unsigned int)f2bf(accO[f][g4 * 4 + 0] * linv) |
                        ((unsigned int)f2bf(accO[f][g4 * 4 + 1] * linv) << 16);
      unsigned int hi2 = (unsigned int)f2bf(accO[f][g4 * 4 + 2] * linv) |
                         ((unsigned int)f2bf(accO[f][g4 * 4 + 3] * linv) << 16);
      *(uint2*)(orow + f * 32 + 8 * g4 + 4 * hi) = make_uint2(lo, hi2);
    }
}

extern "C" void kernel_launch(void* const* d_in, const int* in_sizes, int n_in,
                              void* d_out, int out_size, void* d_ws, size_t ws_size,
                              hipStream_t stream) {
  (void)in_sizes; (void)n_in; (void)out_size; (void)ws_size;
  const float* x  = (const float*)d_in[0];
  const float* fc = (const float*)d_in[1];
  // d_in[2] = mask: exactly triu(-1e9, k=1) -> causal handled in-kernel
  const float* wq = (const float*)d_in[3];
  const float* wk = (const float*)d_in[4];
  const float* wv = (const float*)d_in[5];
  const float* wo = (const float*)d_in[6];

  const size_t M = 1024 * 1024;
  unsigned short* xb   = (unsigned short*)d_ws;      // 8M shorts; reused as Ab after GEMM1
  unsigned short* wfus = xb   + 8 * M;               // 24M: [wq 4096 | wk 1024 | wv 1024][4096]
  unsigned short* wob  = wfus + 24 * M;              // 16M
  unsigned short* QKV  = wob  + 16 * M;              // 12M: [2048][6144] = Q|K|V (Q,K roped)
  unsigned short* Ktil = QKV  + 12 * M;              // 2M  tiled K images
  unsigned short* Vtil = Ktil + 2 * M;               // 2M  tiled V^T images
  unsigned short* Ab   = xb;                         // alias: xb dead after GEMM1

  cvtk<<<dim3(8 * M / 1024), 256, 0, stream>>>(x, xb, 8 * M);
  cvtk<<<dim3(16 * M / 1024), 256, 0, stream>>>(wq, wfus, 16 * M);
  cvtk<<<dim3(4 * M / 1024), 256, 0, stream>>>(wk, wfus + 16 * M, 4 * M);
  cvtk<<<dim3(4 * M / 1024), 256, 0, stream>>>(wv, wfus + 20 * M, 4 * M);
  cvtk<<<dim3(16 * M / 1024), 256, 0, stream>>>(wo, wob, 16 * M);

  // fused QKV projection + RoPE: [2048][6144] = xb @ wfus^T   (256 blocks, full chip)
  gemm_qkv<<<dim3(256), 512, 0, stream>>>(xb, wfus, fc, QKV);

  ktile<<<dim3(512), 256, 0, stream>>>(QKV, Ktil);
  vtile<<<dim3(512), 256, 0, stream>>>(QKV, Vtil);

  attnk<<<dim3(512), 256, 0, stream>>>(QKV, Ktil, Vtil, Ab);

  // output projection (256 blocks, full chip)
  gemm_o<<<dim3(256), 512, 0, stream>>>(Ab, wob, (float*)d_out);
}

// Round 7
// 378.314 us; speedup vs baseline: 1.1229x; 1.1229x over previous
//
#include <hip/hip_runtime.h>
#include <stdint.h>

// Problem constants: B=1, S=2048, D=4096, H=32, KV=8, HD=128, NREP=4
#define SCALE_F 0.08838834764831845f
#define LOG2E_F 1.4426950408889634f
#define QS_F (SCALE_F * LOG2E_F)

typedef __bf16 bf16x8_t __attribute__((ext_vector_type(8)));
typedef unsigned short u16x8 __attribute__((ext_vector_type(8)));
typedef float f32x4 __attribute__((ext_vector_type(4)));
typedef float f32x16 __attribute__((ext_vector_type(16)));

__device__ __forceinline__ unsigned short f2bf(float f) {
  unsigned int u = __float_as_uint(f);
  unsigned int r = ((u >> 16) & 1u) + 0x7FFFu;  // RNE
  return (unsigned short)((u + r) >> 16);
}
__device__ __forceinline__ float bf2f(unsigned short s) {
  return __uint_as_float(((unsigned int)s) << 16);
}
__device__ __forceinline__ f32x4 mfma16(u16x8 a, u16x8 b, f32x4 c) {
  return __builtin_amdgcn_mfma_f32_16x16x32_bf16(
      __builtin_bit_cast(bf16x8_t, a), __builtin_bit_cast(bf16x8_t, b), c, 0, 0, 0);
}
__device__ __forceinline__ f32x16 mfma32(u16x8 a, u16x8 b, f32x16 c) {
  return __builtin_amdgcn_mfma_f32_32x32x16_bf16(
      __builtin_bit_cast(bf16x8_t, a), __builtin_bit_cast(bf16x8_t, b), c, 0, 0, 0);
}
__device__ __forceinline__ unsigned int cvtpk(float lo, float hi) {
  unsigned int r;
  asm("v_cvt_pk_bf16_f32 %0, %1, %2" : "=v"(r) : "v"(lo), "v"(hi));
  return r;
}
__device__ __forceinline__ float exp2_hw(float x) {  // D = 2^S0
  float r;
  asm("v_exp_f32 %0, %1" : "=v"(r) : "v"(x));
  return r;
}
__device__ __forceinline__ void gload_lds16(const void* g, void* l) {
  __builtin_amdgcn_global_load_lds((const __attribute__((address_space(1))) void*)g,
                                   (__attribute__((address_space(3))) void*)l, 16, 0, 0);
}
#define LGKM0_SB() do { \
  asm volatile("s_waitcnt lgkmcnt(0)" ::: "memory"); \
  __builtin_amdgcn_sched_barrier(0); } while (0)

// ---------------- f32 -> bf16 convert ----------------
__global__ void cvtk(const float* __restrict__ in, unsigned short* __restrict__ out, int n) {
  int i = (blockIdx.x * blockDim.x + threadIdx.x) * 4;
  if (i >= n) return;
  float4 v = *(const float4*)(in + i);
  unsigned int p0 = (unsigned int)f2bf(v.x) | ((unsigned int)f2bf(v.y) << 16);
  unsigned int p1 = (unsigned int)f2bf(v.z) | ((unsigned int)f2bf(v.w) << 16);
  *(uint2*)(out + i) = make_uint2(p0, p1);
}

// ---------------- K: retile into chunk-transposed tile images (rope pre-applied) ----
__global__ void ktile(const unsigned short* __restrict__ QKV, unsigned short* __restrict__ Ktil) {
  int b = blockIdx.x;  // kvg*64 + kvt
  int kvg = b >> 6, kvt = b & 63;
  int tid = threadIdx.x;
#pragma unroll
  for (int cc = 0; cc < 2; ++cc) {
    int c = tid + cc * 256;
    int s = c >> 5, r = c & 31;
    int key = kvt * 32 + r;
    *(uint4*)&Ktil[(size_t)b * 4096 + c * 8] =
        *(const uint4*)&QKV[(size_t)key * 6144 + 4096 + kvg * 128 + s * 8];
  }
}

// ---------------- V: transpose + retile ----------------
__global__ void vtile(const unsigned short* __restrict__ QKV, unsigned short* __restrict__ Vtil) {
  int b = blockIdx.x;  // kvg*64 + kvt
  int kvg = b >> 6, kvt = b & 63;
  int tid = threadIdx.x;
#pragma unroll
  for (int cc = 0; cc < 2; ++cc) {
    int c = tid + cc * 256;
    int v = c >> 7, hd = c & 127;
    unsigned short o[8];
#pragma unroll
    for (int t = 0; t < 8; ++t)
      o[t] = QKV[(size_t)(kvt * 32 + v * 8 + t) * 6144 + 5120 + kvg * 128 + hd];
    *(uint4*)&Vtil[(size_t)b * 4096 + c * 8] = *(uint4*)o;
  }
}

// ---------------- QKV GEMM: 256x192 tiles, 256 blocks, fused RoPE epilogue ----------------
// Spread staging (s0:A0,s1:A1,s2:B0,s3:B1,s4:A2,s5:A3,s6:B2 per tile for t+1) with
// counted vmcnt and only TWO barriers per K-tile (mid-tile + boundary) — barriers only at
// cross-wave consumption boundaries; own-wave ds_read->MFMA ordering via lgkmcnt(0).
// FIFO invariant entering tile t: {A0,A1,B0,B1}(t) landed+published, {A2,A3,B2}(t)
// outstanding(own). midwait vmcnt(4) drains them; endwait vmcnt(3) drains t+1's kc0 set.
__global__ __launch_bounds__(512, 2) void gemm_qkv(const unsigned short* __restrict__ A,
                                                   const unsigned short* __restrict__ BT,
                                                   const float* __restrict__ fc,
                                                   unsigned short* __restrict__ C) {
  const int K = 4096, N = 6144;
  __shared__ __align__(16) unsigned short smem[2 * 28672];  // 112 KiB
  const int tid = threadIdx.x;
  const int w = tid >> 6, l = tid & 63;
  const int wm = w >> 2, wn = w & 3;
  const int c16 = l & 15, h4 = l >> 4;
  const int wg = ((int)blockIdx.x & 7) * 32 + ((int)blockIdx.x >> 3);  // T1 XCD swizzle
  const int m0 = (wg & 7) << 8, n0 = (wg >> 3) * 192;

  int growA[4], gcolA[4], growB[3], gcolB[3];
#pragma unroll
  for (int p = 0; p < 4; ++p) {
    int c = p * 512 + tid, ll = c & 63;
    growA[p] = ((c >> 6) & 15) * 16 + (ll & 15);
    gcolA[p] = (c >> 10) * 32 + ((ll >> 4) << 3);
  }
#pragma unroll
  for (int p = 0; p < 3; ++p) {
    int c = p * 512 + tid, ll = c & 63, f6 = c >> 6;
    int kc = (f6 >= 12) ? 1 : 0;
    growB[p] = (f6 - 12 * kc) * 16 + (ll & 15);
    gcolB[p] = kc * 32 + ((ll >> 4) << 3);
  }
  auto stageA = [&](int e, int ks, int p) {
    gload_lds16(A + (size_t)(m0 + growA[p]) * K + ks + gcolA[p],
                &smem[e * 28672 + (p * 512 + tid) * 8]);
  };
  auto stageB = [&](int e, int ks, int p) {
    gload_lds16(BT + (size_t)(n0 + growB[p]) * K + ks + gcolB[p],
                &smem[e * 28672 + 16384 + (p * 512 + tid) * 8]);
  };

  f32x4 acc[2][4][3];
#pragma unroll
  for (int mh = 0; mh < 2; ++mh)
#pragma unroll
    for (int mf = 0; mf < 4; ++mf)
#pragma unroll
      for (int nf = 0; nf < 3; ++nf)
#pragma unroll
        for (int r = 0; r < 4; ++r) acc[mh][mf][nf][r] = 0.f;

  // prologue: tile 0 -> slot 0, stage order = loop order; establish invariant
  stageA(0, 0, 0); stageA(0, 0, 1); stageB(0, 0, 0); stageB(0, 0, 1);
  stageA(0, 0, 2); stageA(0, 0, 3); stageB(0, 0, 2);
  asm volatile("s_waitcnt vmcnt(3)" ::: "memory");
  __builtin_amdgcn_sched_barrier(0);
  asm volatile("s_barrier" ::: "memory");

  const int nt = K >> 6;
  for (int t = 0; t < nt; ++t) {
    const int d = t & 1, e = d ^ 1;
    const int dA = d * 28672, dB = dA + 16384;
    const int ks = ((t + 1 < nt) ? t + 1 : t) << 6;  // clamp: redundant, never read
    u16x8 af[4], bfr[3];
    // ---- superphase kc0 ----
#pragma unroll
    for (int mf = 0; mf < 4; ++mf)
      af[mf] = *(const u16x8*)&smem[dA + ((wm * 8 + mf) * 64 + l) * 8];
#pragma unroll
    for (int nf = 0; nf < 3; ++nf)
      bfr[nf] = *(const u16x8*)&smem[dB + ((wn * 3 + nf) * 64 + l) * 8];
    stageA(e, ks, 0); stageA(e, ks, 1);
    LGKM0_SB();
    __builtin_amdgcn_s_setprio(1);
#pragma unroll
    for (int mf = 0; mf < 4; ++mf)
#pragma unroll
      for (int nf = 0; nf < 3; ++nf)
        acc[0][mf][nf] = mfma16(af[mf], bfr[nf], acc[0][mf][nf]);
    __builtin_amdgcn_s_setprio(0);
    __builtin_amdgcn_sched_barrier(0);
#pragma unroll
    for (int mf = 0; mf < 4; ++mf)
      af[mf] = *(const u16x8*)&smem[dA + ((wm * 8 + 4 + mf) * 64 + l) * 8];
    stageB(e, ks, 0); stageB(e, ks, 1);
    LGKM0_SB();
    __builtin_amdgcn_s_setprio(1);
#pragma unroll
    for (int mf = 0; mf < 4; ++mf)
#pragma unroll
      for (int nf = 0; nf < 3; ++nf)
        acc[1][mf][nf] = mfma16(af[mf], bfr[nf], acc[1][mf][nf]);
    __builtin_amdgcn_s_setprio(0);
    __builtin_amdgcn_sched_barrier(0);
    asm volatile("s_waitcnt vmcnt(4)" ::: "memory");  // t's kc1 parts landed
    asm volatile("s_barrier" ::: "memory");           // publish
    // ---- superphase kc1 ----
#pragma unroll
    for (int mf = 0; mf < 4; ++mf)
      af[mf] = *(const u16x8*)&smem[dA + ((16 + wm * 8 + mf) * 64 + l) * 8];
#pragma unroll
    for (int nf = 0; nf < 3; ++nf)
      bfr[nf] = *(const u16x8*)&smem[dB + ((12 + wn * 3 + nf) * 64 + l) * 8];
    stageA(e, ks, 2); stageA(e, ks, 3);
    LGKM0_SB();
    __builtin_amdgcn_s_setprio(1);
#pragma unroll
    for (int mf = 0; mf < 4; ++mf)
#pragma unroll
      for (int nf = 0; nf < 3; ++nf)
        acc[0][mf][nf] = mfma16(af[mf], bfr[nf], acc[0][mf][nf]);
    __builtin_amdgcn_s_setprio(0);
    __builtin_amdgcn_sched_barrier(0);
#pragma unroll
    for (int mf = 0; mf < 4; ++mf)
      af[mf] = *(const u16x8*)&smem[dA + ((16 + wm * 8 + 4 + mf) * 64 + l) * 8];
    stageB(e, ks, 2);
    LGKM0_SB();
    __builtin_amdgcn_s_setprio(1);
#pragma unroll
    for (int mf = 0; mf < 4; ++mf)
#pragma unroll
      for (int nf = 0; nf < 3; ++nf)
        acc[1][mf][nf] = mfma16(af[mf], bfr[nf], acc[1][mf][nf]);
    __builtin_amdgcn_s_setprio(0);
    __builtin_amdgcn_sched_barrier(0);
    asm volatile("s_waitcnt vmcnt(3)" ::: "memory");  // t+1's kc0 parts landed
    asm volatile("s_barrier" ::: "memory");           // boundary
  }
  asm volatile("s_waitcnt vmcnt(0)" ::: "memory");

  // epilogue with fused RoPE (cols<4096: Q rope * SCALE*log2e; 4096..5119: K rope;
  // >=5120: V passthrough). Pair partner in adjacent lane: shfl_xor(1).
#pragma unroll
  for (int mh = 0; mh < 2; ++mh)
#pragma unroll
    for (int mf = 0; mf < 4; ++mf)
#pragma unroll
      for (int nf = 0; nf < 3; ++nf) {
        const int colbase = n0 + wn * 48 + nf * 16;
#pragma unroll
        for (int r = 0; r < 4; ++r) {
          int row = m0 + wm * 128 + mh * 64 + mf * 16 + h4 * 4 + r;
          float v = acc[mh][mf][nf][r];
          if (colbase < 5120) {
            float other = __shfl_xor(v, 1, 64);
            int j = ((colbase & 127) >> 1) + (c16 >> 1);
            float2 csn = *(const float2*)&fc[((size_t)row * 64 + j) * 2];
            float o = (c16 & 1) ? (other * csn.y + v * csn.x) : (v * csn.x - other * csn.y);
            v = (colbase < 4096) ? o * QS_F : o;
          }
          C[(size_t)row * N + colbase + c16] = f2bf(v);
        }
      }
}

// ---------------- Out-proj GEMM: 128x256 tiles, 256 blocks, f32 out ----------------
// Same 2-barrier counted-vmcnt schedule. Stage order s0:A0,s1:B0,s2:B1 (kc0 set),
// s3:A1,s4:B2,s5:B3 (kc1 set). Invariant entering t: kc0 set landed, kc1 set (3)
// outstanding. midwait vmcnt(3); endwait vmcnt(3).
__global__ __launch_bounds__(512, 2) void gemm_o(const unsigned short* __restrict__ A,
                                                 const unsigned short* __restrict__ BT,
                                                 float* __restrict__ C) {
  const int K = 4096, N = 4096;
  __shared__ __align__(16) unsigned short smem[2 * 24576];  // 96 KiB
  const int tid = threadIdx.x;
  const int w = tid >> 6, l = tid & 63;
  const int wm = w >> 2, wn = w & 3;
  const int c16 = l & 15, h4 = l >> 4;
  const int wg = ((int)blockIdx.x & 7) * 32 + ((int)blockIdx.x >> 3);  // T1 XCD swizzle
  const int m0 = (wg & 15) << 7, n0 = (wg >> 4) << 8;

  int growA[2], gcolA[2], growB[4], gcolB[4];
#pragma unroll
  for (int p = 0; p < 2; ++p) {
    int c = p * 512 + tid, ll = c & 63;
    growA[p] = ((c >> 6) & 7) * 16 + (ll & 15);
    gcolA[p] = (c >> 9) * 32 + ((ll >> 4) << 3);
  }
#pragma unroll
  for (int p = 0; p < 4; ++p) {
    int c = p * 512 + tid, ll = c & 63;
    growB[p] = ((c >> 6) & 15) * 16 + (ll & 15);
    gcolB[p] = (c >> 10) * 32 + ((ll >> 4) << 3);
  }
  auto stageA = [&](int e, int ks, int p) {
    gload_lds16(A + (size_t)(m0 + growA[p]) * K + ks + gcolA[p],
                &smem[e * 24576 + (p * 512 + tid) * 8]);
  };
  auto stageB = [&](int e, int ks, int p) {
    gload_lds16(BT + (size_t)(n0 + growB[p]) * K + ks + gcolB[p],
                &smem[e * 24576 + 8192 + (p * 512 + tid) * 8]);
  };

  f32x4 acc[4][4];
#pragma unroll
  for (int mf = 0; mf < 4; ++mf)
#pragma unroll
    for (int nc = 0; nc < 4; ++nc)
#pragma unroll
      for (int r = 0; r < 4; ++r) acc[mf][nc][r] = 0.f;

  stageA(0, 0, 0); stageB(0, 0, 0); stageB(0, 0, 1);
  stageA(0, 0, 1); stageB(0, 0, 2); stageB(0, 0, 3);
  asm volatile("s_waitcnt vmcnt(3)" ::: "memory");
  __builtin_amdgcn_sched_barrier(0);
  asm volatile("s_barrier" ::: "memory");

  const int nt = K >> 6;
  for (int t = 0; t < nt; ++t) {
    const int d = t & 1, e = d ^ 1;
    const int dA = d * 24576, dB = dA + 8192;
    const int ks = ((t + 1 < nt) ? t + 1 : t) << 6;
    u16x8 af[4], bfr[4];
    // ---- superphase kc0 ----
#pragma unroll
    for (int mf = 0; mf < 4; ++mf)
      af[mf] = *(const u16x8*)&smem[dA + ((wm * 4 + mf) * 64 + l) * 8];
#pragma unroll
    for (int nc = 0; nc < 4; ++nc)
      bfr[nc] = *(const u16x8*)&smem[dB + ((wn * 4 + nc) * 64 + l) * 8];
    stageA(e, ks, 0); stageB(e, ks, 0); stageB(e, ks, 1);
    LGKM0_SB();
    __builtin_amdgcn_s_setprio(1);
#pragma unroll
    for (int mf = 0; mf < 4; ++mf)
#pragma unroll
      for (int nc = 0; nc < 4; ++nc)
        acc[mf][nc] = mfma16(af[mf], bfr[nc], acc[mf][nc]);
    __builtin_amdgcn_s_setprio(0);
    __builtin_amdgcn_sched_barrier(0);
    asm volatile("s_waitcnt vmcnt(3)" ::: "memory");  // t's kc1 set landed
    asm volatile("s_barrier" ::: "memory");           // publish
    // ---- superphase kc1 ----
#pragma unroll
    for (int mf = 0; mf < 4; ++mf)
      af[mf] = *(const u16x8*)&smem[dA + ((8 + wm * 4 + mf) * 64 + l) * 8];
#pragma unroll
    for (int nc = 0; nc < 4; ++nc)
      bfr[nc] = *(const u16x8*)&smem[dB + ((16 + wn * 4 + nc) * 64 + l) * 8];
    stageA(e, ks, 1); stageB(e, ks, 2); stageB(e, ks, 3);
    LGKM0_SB();
    __builtin_amdgcn_s_setprio(1);
#pragma unroll
    for (int mf = 0; mf < 4; ++mf)
#pragma unroll
      for (int nc = 0; nc < 4; ++nc)
        acc[mf][nc] = mfma16(af[mf], bfr[nc], acc[mf][nc]);
    __builtin_amdgcn_s_setprio(0);
    __builtin_amdgcn_sched_barrier(0);
    asm volatile("s_waitcnt vmcnt(3)" ::: "memory");  // t+1's kc0 set landed
    asm volatile("s_barrier" ::: "memory");           // boundary
  }
  asm volatile("s_waitcnt vmcnt(0)" ::: "memory");

#pragma unroll
  for (int mf = 0; mf < 4; ++mf)
#pragma unroll
    for (int nc = 0; nc < 4; ++nc)
#pragma unroll
      for (int r = 0; r < 4; ++r) {
        int row = m0 + wm * 64 + mf * 16 + h4 * 4 + r;
        int col = n0 + wn * 64 + nc * 16 + c16;
        C[(size_t)row * N + col] = acc[mf][nc][r];
      }
}

// ---------------- flash attention (causal GQA), 32x32x16 swapped-MFMA ----------------
__global__ __launch_bounds__(256) void attnk(const unsigned short* __restrict__ Q,
                                             const unsigned short* __restrict__ Ktil,
                                             const unsigned short* __restrict__ Vtil,
                                             unsigned short* __restrict__ Ao) {
  __shared__ __align__(16) unsigned short Kbuf[2][4096];  // 8KB per buffer
  __shared__ __align__(16) unsigned short Vbuf[2][4096];
  const int tid = threadIdx.x;
  const int w = tid >> 6, l = tid & 63;
  const int q31 = l & 31, hi = l >> 5;
  const int b = blockIdx.x;
  const int kvg = b & 7;             // kv-group -> XCD affinity
  const int qg = 63 - (b >> 3);      // descending work length for backfill balance
  const int head = kvg * 4 + w;
  const int qrow = qg * 32 + q31;

  u16x8 qf[8];
#pragma unroll
  for (int kc = 0; kc < 8; ++kc)
    qf[kc] = *(const u16x8*)&Q[(size_t)qrow * 6144 + head * 128 + kc * 16 + hi * 8];

  f32x16 accO[4];
#pragma unroll
  for (int f = 0; f < 4; ++f)
#pragma unroll
    for (int r = 0; r < 16; ++r) accO[f][r] = 0.f;
  float m_run = -1e30f, l_run = 0.f;

  const unsigned short* ktb = Ktil + (size_t)kvg * 64 * 4096;
  const unsigned short* vtb = Vtil + (size_t)kvg * 64 * 4096;
  auto STAGE = [&](int d, int t) {
    const unsigned short* ks = ktb + (size_t)t * 4096 + w * 1024 + l * 8;
    const unsigned short* vs = vtb + (size_t)t * 4096 + w * 1024 + l * 8;
    gload_lds16(ks, &Kbuf[d][w * 1024 + l * 8]);
    gload_lds16(ks + 512, &Kbuf[d][w * 1024 + 512 + l * 8]);
    gload_lds16(vs, &Vbuf[d][w * 1024 + l * 8]);
    gload_lds16(vs + 512, &Vbuf[d][w * 1024 + 512 + l * 8]);
  };

  STAGE(0, 0);
  int cur = 0;
  for (int kvt = 0; kvt <= qg; ++kvt) {
    __builtin_amdgcn_s_barrier();
    __builtin_amdgcn_sched_barrier(0);
    if (kvt < qg) {
      STAGE(cur ^ 1, kvt + 1);
      asm volatile("s_waitcnt vmcnt(4)" ::: "memory");
    } else {
      asm volatile("s_waitcnt vmcnt(0)" ::: "memory");
    }
    __builtin_amdgcn_s_barrier();
    __builtin_amdgcn_sched_barrier(0);

    f32x16 s;
#pragma unroll
    for (int r = 0; r < 16; ++r) s[r] = 0.f;
#pragma unroll
    for (int kc = 0; kc < 8; ++kc) {
      u16x8 kf = *(const u16x8*)&Kbuf[cur][((2 * kc + hi) * 32 + q31) * 8];
      s = mfma32(kf, qf[kc], s);
    }

    if (kvt == qg) {
#pragma unroll
      for (int r = 0; r < 16; ++r) {
        int key = (r & 3) + 8 * (r >> 2) + 4 * hi;
        if (key > q31) s[r] = -1e30f;
      }
    }

    float pm = s[0];
#pragma unroll
    for (int r = 1; r < 16; ++r) pm = fmaxf(pm, s[r]);
    pm = fmaxf(pm, __shfl_xor(pm, 32, 64));
    if (!__all(pm - m_run <= 8.f)) {  // T13 defer-max (2^8 bound)
      float mn = fmaxf(m_run, pm);
      float al = exp2_hw(m_run - mn);
      m_run = mn;
      l_run *= al;
#pragma unroll
      for (int f = 0; f < 4; ++f)
#pragma unroll
        for (int r = 0; r < 16; ++r) accO[f][r] *= al;
    }
    float p[16], ls = 0.f;
#pragma unroll
    for (int r = 0; r < 16; ++r) { p[r] = exp2_hw(s[r] - m_run); ls += p[r]; }
    l_run += ls + __shfl_xor(ls, 32, 64);

    unsigned int wv[8], wp[8];
#pragma unroll
    for (int i = 0; i < 8; ++i) wv[i] = cvtpk(p[2 * i], p[2 * i + 1]);
#pragma unroll
    for (int i = 0; i < 8; ++i) wp[i] = (unsigned int)__shfl_xor((int)wv[i], 32, 64);
    union { unsigned int u[4]; u16x8 v; } pf0, pf1;
    pf0.u[0] = hi ? wp[2] : wv[0];
    pf0.u[1] = hi ? wp[3] : wv[1];
    pf0.u[2] = hi ? wv[2] : wp[0];
    pf0.u[3] = hi ? wv[3] : wp[1];
    pf1.u[0] = hi ? wp[6] : wv[4];
    pf1.u[1] = hi ? wp[7] : wv[5];
    pf1.u[2] = hi ? wv[6] : wp[4];
    pf1.u[3] = hi ? wv[7] : wp[5];

#pragma unroll
    for (int f = 0; f < 4; ++f) {
      u16x8 vf0 = *(const u16x8*)&Vbuf[cur][((hi) * 128 + f * 32 + q31) * 8];
      u16x8 vf1 = *(const u16x8*)&Vbuf[cur][((2 + hi) * 128 + f * 32 + q31) * 8];
      accO[f] = mfma32(vf0, pf0.v, accO[f]);
      accO[f] = mfma32(vf1, pf1.v, accO[f]);
    }
    cur ^= 1;
  }

  float linv = 1.0f / l_run;
  unsigned short* orow = Ao + (size_t)qrow * 4096 + head * 128;
#pragma unroll
  for (int f = 0; f < 4; ++f)
#pragma unroll
    for (int g4 = 0; g4 < 4; ++g4) {
      unsigned int lo = (unsigned int)f2bf(accO[f][g4 * 4 + 0] * linv) |
                        ((unsigned int)f2bf(accO[f][g4 * 4 + 1] * linv) << 16);
      unsigned int hi2 = (unsigned int)f2bf(accO[f][g4 * 4 + 2] * linv) |
                         ((unsigned int)f2bf(accO[f][g4 * 4 + 3] * linv) << 16);
      *(uint2*)(orow + f * 32 + 8 * g4 + 4 * hi) = make_uint2(lo, hi2);
    }
}

extern "C" void kernel_launch(void* const* d_in, const int* in_sizes, int n_in,
                              void* d_out, int out_size, void* d_ws, size_t ws_size,
                              hipStream_t stream) {
  (void)in_sizes; (void)n_in; (void)out_size; (void)ws_size;
  const float* x  = (const float*)d_in[0];
  const float* fc = (const float*)d_in[1];
  // d_in[2] = mask: exactly triu(-1e9, k=1) -> causal handled in-kernel
  const float* wq = (const float*)d_in[3];
  const float* wk = (const float*)d_in[4];
  const float* wv = (const float*)d_in[5];
  const float* wo = (const float*)d_in[6];

  const size_t M = 1024 * 1024;
  unsigned short* xb   = (unsigned short*)d_ws;      // 8M shorts; reused as Ab after GEMM1
  unsigned short* wfus = xb   + 8 * M;               // 24M: [wq 4096 | wk 1024 | wv 1024][4096]
  unsigned short* wob  = wfus + 24 * M;              // 16M
  unsigned short* QKV  = wob  + 16 * M;              // 12M: [2048][6144] = Q|K|V (Q,K roped)
  unsigned short* Ktil = QKV  + 12 * M;              // 2M  tiled K images
  unsigned short* Vtil = Ktil + 2 * M;               // 2M  tiled V^T images
  unsigned short* Ab   = xb;                         // alias: xb dead after GEMM1

  cvtk<<<dim3(8 * M / 1024), 256, 0, stream>>>(x, xb, 8 * M);
  cvtk<<<dim3(16 * M / 1024), 256, 0, stream>>>(wq, wfus, 16 * M);
  cvtk<<<dim3(4 * M / 1024), 256, 0, stream>>>(wk, wfus + 16 * M, 4 * M);
  cvtk<<<dim3(4 * M / 1024), 256, 0, stream>>>(wv, wfus + 20 * M, 4 * M);
  cvtk<<<dim3(16 * M / 1024), 256, 0, stream>>>(wo, wob, 16 * M);

  // fused QKV projection + RoPE: [2048][6144] = xb @ wfus^T   (256 blocks, full chip)
  gemm_qkv<<<dim3(256), 512, 0, stream>>>(xb, wfus, fc, QKV);

  ktile<<<dim3(512), 256, 0, stream>>>(QKV, Ktil);
  vtile<<<dim3(512), 256, 0, stream>>>(QKV, Vtil);

  attnk<<<dim3(512), 256, 0, stream>>>(QKV, Ktil, Vtil, Ab);

  // output projection (256 blocks, full chip)
  gemm_o<<<dim3(256), 512, 0, stream>>>(Ab, wob, (float*)d_out);
}